// Round 5
// baseline (156.997 us; speedup 1.0000x reference)
//
#include <hip/hip_runtime.h>
#include <stdint.h>

typedef unsigned short u16;
typedef __attribute__((ext_vector_type(8))) short short8;   // 8 x bf16 (4 VGPRs)
typedef __attribute__((ext_vector_type(4))) float f32x4;    // 4 x fp32 acc

typedef __attribute__((address_space(3))) uint8_t* lds_ptr_t;
typedef const __attribute__((address_space(1))) uint8_t* gbl_ptr_t;

__device__ __forceinline__ u16 f2bf(float f) {
    union { float f; uint32_t u; } v; v.f = f;
    return (u16)((v.u + (0x7FFFu + ((v.u >> 16) & 1u))) >> 16);   // RNE
}

// ---------------- P1: W2p = (U@S) packed in MFMA A-fragment order --------------
// frag(wv,ks2,mt) of 512 u16: lane ln=quad*16+o15 holds o=wv*64+mt*16+o15,
// r=ks2*32+quad*8+e. One coalesced 1KB load per fragment in stage B.
__global__ void k_us(const float* __restrict__ U, const float* __restrict__ S,
                     u16* __restrict__ W2p) {
    int t = blockIdx.x * 256 + threadIdx.x;        // 16384 threads
    int o = t >> 6, r = t & 63;
    float acc = 0.f;
#pragma unroll 8
    for (int i = 0; i < 64; ++i) acc += U[o * 64 + i] * S[i * 64 + r];
    int wv = o >> 6, mt = (o >> 4) & 3, o15 = o & 15;
    int ks2 = r >> 5, quad = (r >> 3) & 3, e = r & 7;
    W2p[(((wv * 2 + ks2) * 4 + mt) * 64 + quad * 16 + o15) * 8 + e] = f2bf(acc);
}

// ---------------- P2: Vp = V packed in exact MFMA A-fragment order -------------
// frag(kv,tap,cc,mt): 1024 B, lane ln holds 16 B: A[m=mt*16+(ln&15)]
// [k=quad*8+e] with c = kv*64+cc*32+quad*8+e.
__global__ void k_vpack(const float* __restrict__ V, u16* __restrict__ Vp) {
    int t = blockIdx.x * 256 + threadIdx.x;        // 18432 threads (72 blocks)
    int ln = t & 63, mt = (t >> 6) & 3, cc = (t >> 8) & 1;
    int tap = (t >> 9) % 9, kv = t / 4608;
    int r = mt * 16 + (ln & 15);
    int cb = kv * 64 + cc * 32 + (ln >> 4) * 8;
    u16 tmp[8];
#pragma unroll
    for (int e = 0; e < 8; ++e)
        tmp[e] = f2bf(V[(size_t)((cb + e) * 9 + tap) * 64 + r]);
    *(uint4*)(Vp + (size_t)t * 8) = *(uint4*)tmp;
}

// ---------------- P3: coalesced LDS-tiled transpose+pad  -----------------------
// xb[b][hp][wp][c] (bf16, [16][58][58][256]) from x[b][c][h][w] fp32.
__global__ __launch_bounds__(256) void k_tr(const float* __restrict__ x,
                                            u16* __restrict__ xb) {
    __shared__ uint32_t lds[64 * 57];               // 14592 B
    int bi = blockIdx.x;                            // 16*58*2 = 1856
    int cg = bi & 1;
    int hp = (bi >> 1) % 58;
    int b  = bi / 116;
    int c0 = cg * 128;
    int tid = threadIdx.x;

    uint32_t* xbrow32 = (uint32_t*)(xb + ((size_t)(b * 58 + hp) * 58) * 256 + c0);

    if (hp == 0 || hp == 57) {                      // border row: all zeros
        for (int i = tid; i < 58 * 64; i += 256)
            xbrow32[(i >> 6) * 128 + (i & 63)] = 0u;
        return;
    }

    int h = hp - 1;
    int w = tid & 63;                               // 56 valid
    int cpq = tid >> 6;                             // 0..3
    const float* xbase = x + ((size_t)(b * 256 + c0) * 3136) + h * 56 + w;
    if (w < 56) {
#pragma unroll
        for (int k = 0; k < 16; ++k) {
            int cp = cpq * 16 + k;                  // channel pair 0..63
            float a0 = xbase[(size_t)(2 * cp) * 3136];
            float a1 = xbase[(size_t)(2 * cp + 1) * 3136];
            lds[cp * 57 + w] = (uint32_t)f2bf(a0) | ((uint32_t)f2bf(a1) << 16);
        }
    }
    __syncthreads();

    int cpair = tid & 63;
    int wpq = tid >> 6;
#pragma unroll
    for (int wp = wpq; wp < 58; wp += 4) {
        uint32_t v = (wp == 0 || wp == 57) ? 0u : lds[cpair * 57 + (wp - 1)];
        xbrow32[wp * 128 + cpair] = v;
    }
}

// ---------------- Fused conv + stage B ----------------------------------------
// Block = 4h x 16w output tile (896 = 16b x 14ht x 4wt; wt3 starts at w=40,
// overlap w40..47 double-written with identical values). Stage the 6x18x256c
// halo window (55.3 KB) ONCE (wave-split, XOR-swizzled), K-loop with zero
// barriers (K-split-4 over channel quarters), 4-way LDS reduction, then the
// 256x64 stage-B GEMM from an LDS y1-tile + packed W2 frags, add bias, store
// out in 64 B segments.
__global__ __launch_bounds__(256, 2) void k_convAB(const u16* __restrict__ xb,
                                                   const u16* __restrict__ Vp,
                                                   const u16* __restrict__ W2p,
                                                   const float* __restrict__ bias,
                                                   float* __restrict__ out) {
    __shared__ u16 lds[108 * 256];                  // 55296 B
    int bi = blockIdx.x;                            // 896
    int wt = bi & 3, ht = (bi >> 2) % 14, b = bi / 56;
    int h0 = ht * 4;
    int w0 = (wt == 3) ? 40 : wt * 16;
    int tid = threadIdx.x;
    int kv = tid >> 6, ln = tid & 63;               // kv = wave = K-quarter
    int lane15 = ln & 15, quad = ln >> 4;

    // ---- stage 108 cells (6 rows x 18 wp) = 54 x 1KB instrs, split 4 ways ----
    {
        const u16* gw = xb + (((size_t)(b * 58 + h0)) * 58 + w0) * 256;
        char* lb = (char*)lds;
        int j = ln & 31;                            // 16B slice within cell
        int chalf = ln >> 5;                        // which of 2 cells per instr
        for (int i = kv; i < 54; i += 4) {
            int cell = 2 * i + chalf;
            int rr = cell / 18, wc = cell % 18;
            const u16* g = gw + (rr * 58 + wc) * 256 + ((j ^ (cell & 7)) << 3);
            __builtin_amdgcn_global_load_lds((gbl_ptr_t)g,
                                             (lds_ptr_t)(lb + i * 1024), 16, 0, 0);
        }
    }
    __syncthreads();

    // ---- conv K-loop: 9 taps x 2 cc = 18 k-steps, no barriers ----
    const char* lb = (const char*)lds;
    int jbase = (kv << 3) + quad;                   // 16B-slice id: kv*8+cc*4+quad

    f32x4 acc[4][4];
#pragma unroll
    for (int mt = 0; mt < 4; ++mt)
#pragma unroll
        for (int nt = 0; nt < 4; ++nt) acc[mt][nt] = (f32x4){0.f, 0.f, 0.f, 0.f};

#pragma unroll
    for (int tap = 0; tap < 9; ++tap) {
        const int di = tap / 3, dj = tap % 3;
#pragma unroll
        for (int cc = 0; cc < 2; ++cc) {
            const u16* ab = Vp + ((size_t)(((kv * 9 + tap) * 2 + cc) * 4) * 512)
                          + ln * 8;
            short8 a[4];
#pragma unroll
            for (int mt = 0; mt < 4; ++mt)
                a[mt] = *(const short8*)(ab + mt * 512);
            int jj = jbase + (cc << 2);
            short8 bv[4];
#pragma unroll
            for (int nt = 0; nt < 4; ++nt) {
                int cell = (nt + di) * 18 + lane15 + dj;
                int off = cell * 512 + ((jj ^ (cell & 7)) << 4);
                bv[nt] = *(const short8*)(lb + off);
            }
#pragma unroll
            for (int mt = 0; mt < 4; ++mt)
#pragma unroll
                for (int nt = 0; nt < 4; ++nt)
                    acc[mt][nt] = __builtin_amdgcn_mfma_f32_16x16x32_bf16(
                        a[mt], bv[nt], acc[mt][nt], 0, 0, 0);
        }
    }

    // ---- 4-way K-split reduction (reuse x LDS: red 32KB, y1-tile at +36864) ---
    __syncthreads();
    f32x4* red = (f32x4*)lds;
    u16* y1l = (u16*)lds + 18432;                   // byte 36864; 64 x 72 u16
    if (kv & 1) {                                   // kv1 -> red[0..15], kv3 -> [16..31]
        f32x4* dst = red + ((kv >> 1) * 16) * 64;
#pragma unroll
        for (int f = 0; f < 16; ++f) dst[f * 64 + ln] = acc[f >> 2][f & 3];
    }
    __syncthreads();
    if (kv == 0) {
#pragma unroll
        for (int f = 0; f < 16; ++f) acc[f >> 2][f & 3] += red[f * 64 + ln];
    } else if (kv == 2) {
#pragma unroll
        for (int f = 0; f < 16; ++f) red[(16 + f) * 64 + ln] += acc[f >> 2][f & 3];
    }
    __syncthreads();
    if (kv == 0) {                                  // final sum -> bf16 y1 LDS tile
#pragma unroll
        for (int mt = 0; mt < 4; ++mt)
#pragma unroll
            for (int nt = 0; nt < 4; ++nt) {
                f32x4 v = acc[mt][nt] + red[(16 + mt * 4 + nt) * 64 + ln];
                uint2 pv;
                pv.x = (uint32_t)f2bf(v[0]) | ((uint32_t)f2bf(v[1]) << 16);
                pv.y = (uint32_t)f2bf(v[2]) | ((uint32_t)f2bf(v[3]) << 16);
                // y1l[l][r]: l = nt*16+lane15, r = mt*16+quad*4 (stride 72)
                *(uint2*)&y1l[(nt * 16 + lane15) * 72 + mt * 16 + quad * 4] = pv;
            }
    }
    __syncthreads();

    // ---- stage B: out[256 o][64 l] = W2 . y1 + bias; wave kv -> o quarter ----
#pragma unroll
    for (int mt = 0; mt < 4; ++mt)
#pragma unroll
        for (int nt = 0; nt < 4; ++nt) acc[mt][nt] = (f32x4){0.f, 0.f, 0.f, 0.f};

#pragma unroll
    for (int ks2 = 0; ks2 < 2; ++ks2) {
        short8 a2[4];
#pragma unroll
        for (int mt = 0; mt < 4; ++mt)
            a2[mt] = *(const short8*)(W2p + (size_t)((kv * 2 + ks2) * 4 + mt) * 512
                                      + ln * 8);
#pragma unroll
        for (int nt = 0; nt < 4; ++nt) {
            short8 bv = *(const short8*)&y1l[(nt * 16 + lane15) * 72
                                             + ks2 * 32 + quad * 8];
#pragma unroll
            for (int mt = 0; mt < 4; ++mt)
                acc[mt][nt] = __builtin_amdgcn_mfma_f32_16x16x32_bf16(
                    a2[mt], bv, acc[mt][nt], 0, 0, 0);
        }
    }

    int o0 = kv * 64;
#pragma unroll
    for (int mt = 0; mt < 4; ++mt) {
#pragma unroll
        for (int reg = 0; reg < 4; ++reg) {
            int o = o0 + mt * 16 + quad * 4 + reg;
            float bvl = bias[o];
            float* orow = out + ((size_t)(b * 256 + o)) * 3136 + h0 * 56
                        + w0 + lane15;
#pragma unroll
            for (int nt = 0; nt < 4; ++nt)
                orow[nt * 56] = acc[mt][nt][reg] + bvl;
        }
    }
}

extern "C" void kernel_launch(void* const* d_in, const int* in_sizes, int n_in,
                              void* d_out, int out_size, void* d_ws, size_t ws_size,
                              hipStream_t stream) {
    const float* x    = (const float*)d_in[0];   // [16,256,56,56]
    const float* U    = (const float*)d_in[1];   // [256,64]
    const float* S    = (const float*)d_in[2];   // [64,64]
    const float* V    = (const float*)d_in[3];   // [2304,64]
    const float* bias = (const float*)d_in[4];   // [256]
    float* out = (float*)d_out;                  // [16,256,56,56] fp32

    char* ws = (char*)d_ws;
    u16* xb  = (u16*)ws;                                  // 27,557,888 B
    u16* Vp  = (u16*)(ws + 27557888);                     //    294,912 B
    u16* W2p = (u16*)(ws + 27557888 + 294912);            //     32,768 B

    k_us    <<<64,   256, 0, stream>>>(U, S, W2p);
    k_vpack <<<72,   256, 0, stream>>>(V, Vp);
    k_tr    <<<1856, 256, 0, stream>>>(x, xb);
    k_convAB<<<896,  256, 0, stream>>>(xb, Vp, W2p, bias, out);
}